// Round 1
// baseline (78.049 us; speedup 1.0000x reference)
//
#include <hip/hip_runtime.h>
#include <math.h>

#define NTOK 2048
#define HID  128
#define BB   4
#define STATS_BLOCKS 64   // blocks per batch in stats kernel

__device__ __forceinline__ float wave_reduce_add(float v) {
  #pragma unroll
  for (int off = 32; off; off >>= 1) v += __shfl_down(v, off, 64);
  return v;
}

// ---------------- MLP: h = silu(pc@W1+b1)@W2+b2; heads d/r/m ----------------
__global__ __launch_bounds__(256) void mlp_kernel(
    const float* __restrict__ pc,
    const float* __restrict__ W1, const float* __restrict__ b1,
    const float* __restrict__ W2, const float* __restrict__ b2,
    const float* __restrict__ Wd, const float* __restrict__ bd,
    const float* __restrict__ Wr, const float* __restrict__ br,
    const float* __restrict__ Wm, const float* __restrict__ bm,
    float* __restrict__ outd, float* __restrict__ outr, float* __restrict__ outm)
{
  __shared__ float sW2[HID * HID];            // 64 KB
  __shared__ float sW1[2 * HID];
  __shared__ float sb1[HID], sb2[HID], sWd[HID], sWr[HID], sWm[HID];
  __shared__ float sh1[4][HID];               // per-wave hidden activations

  const int tid = threadIdx.x;
  for (int i = tid; i < HID * HID; i += 256) sW2[i] = W2[i];
  if (tid < 2 * HID) sW1[tid] = W1[tid];
  if (tid < HID) {
    sb1[tid] = b1[tid]; sb2[tid] = b2[tid];
    sWd[tid] = Wd[tid]; sWr[tid] = Wr[tid]; sWm[tid] = Wm[tid];
  }
  __syncthreads();

  const int ROWS = 32;                        // rows per block; grid = 8192/32 = 256
  const int wave = tid >> 6, lane = tid & 63;
  const float bdv = bd[0], brv = br[0], bmv = bm[0];

  for (int rr = wave; rr < ROWS; rr += 4) {
    const int row = blockIdx.x * ROWS + rr;   // row in [0, B*N)
    const float x0 = pc[row * 2 + 0];
    const float x1 = pc[row * 2 + 1];
    float* h1 = sh1[wave];
    #pragma unroll
    for (int u = 0; u < 2; ++u) {
      const int j = lane + 64 * u;
      const float z = x0 * sW1[j] + x1 * sW1[HID + j] + sb1[j];
      h1[j] = z / (1.0f + __expf(-z));        // silu
    }
    __syncthreads();
    const int j0 = lane, j1 = lane + 64;
    float a0 = sb2[j0], a1 = sb2[j1];
    #pragma unroll 4
    for (int k = 0; k < HID; ++k) {
      const float hk = h1[k];
      a0 += hk * sW2[k * HID + j0];
      a1 += hk * sW2[k * HID + j1];
    }
    float dd = a0 * sWd[j0] + a1 * sWd[j1];
    float rv = a0 * sWr[j0] + a1 * sWr[j1];
    float mv = a0 * sWm[j0] + a1 * sWm[j1];
    dd = wave_reduce_add(dd);
    rv = wave_reduce_add(rv);
    mv = wave_reduce_add(mv);
    if (lane == 0) {
      outd[row] = dd + bdv;
      outr[row] = rv + brv;
      outm[row] = mv + bmv;
    }
    __syncthreads();
  }
}

// ------------- Stats: per-block partial sum/sumsq of dist_sq ---------------
__global__ __launch_bounds__(256) void stats_kernel(
    const float* __restrict__ pc, double* __restrict__ part)
{
  const int b = blockIdx.y;
  __shared__ float sr[NTOK * 2];              // 16 KB: this batch's coords
  for (int i = threadIdx.x; i < NTOK; i += 256)
    ((float2*)sr)[i] = ((const float2*)(pc + (size_t)b * NTOK * 2))[i];
  __syncthreads();

  float sum = 0.f, ssq = 0.f;
  const int stride = gridDim.x * 256;
  for (int idx = blockIdx.x * 256 + threadIdx.x; idx < NTOK * NTOK; idx += stride) {
    const int s = idx >> 11;                  // idx / 2048
    const int t = idx & (NTOK - 1);
    const float d0 = sr[2 * s]     * (1.0f - sr[2 * t]);
    const float d1 = sr[2 * s + 1] * (1.0f - sr[2 * t + 1]);
    const float q = d0 * d0 + d1 * d1;
    sum += q;
    ssq += q * q;
  }
  sum = wave_reduce_add(sum);
  ssq = wave_reduce_add(ssq);

  __shared__ float red[4][2];
  const int wave = threadIdx.x >> 6, lane = threadIdx.x & 63;
  if (lane == 0) { red[wave][0] = sum; red[wave][1] = ssq; }
  __syncthreads();
  if (threadIdx.x == 0) {
    const float s4 = red[0][0] + red[1][0] + red[2][0] + red[3][0];
    const float q4 = red[0][1] + red[1][1] + red[2][1] + red[3][1];
    double* p = part + ((size_t)b * gridDim.x + blockIdx.x) * 2;
    p[0] = (double)s4;
    p[1] = (double)q4;
  }
}

// ------- Finalize: threshold[b] = mean + 1.25*std(ddof=1), clipped ---------
__global__ void finalize_kernel(const double* __restrict__ part, float* __restrict__ thr)
{
  const int b = threadIdx.x;
  if (b < BB) {
    double s = 0.0, q = 0.0;
    for (int i = 0; i < STATS_BLOCKS; ++i) {
      s += part[((size_t)b * STATS_BLOCKS + i) * 2];
      q += part[((size_t)b * STATS_BLOCKS + i) * 2 + 1];
    }
    const double M = (double)NTOK * (double)NTOK;
    const double mean = s / M;
    double var = (q - s * s / M) / (M - 1.0);
    if (var < 0.0) var = 0.0;
    double sd = sqrt(var);
    if (sd < 1e-6) sd = 1e-6;
    thr[b] = (float)(mean + 1.25 * sd);
  }
}

// ---- Attn: fused bias/mask/rowsum/normalize/write + diffusion_field -------
__global__ __launch_bounds__(256) void attn_kernel(
    const float* __restrict__ pc, const float* __restrict__ diffu,
    const float* __restrict__ thr,
    float* __restrict__ attn, float* __restrict__ dfield)
{
  const int b = blockIdx.y;
  const int s0 = blockIdx.x * 4;
  __shared__ float sr[NTOK * 2];              // 16 KB coords
  __shared__ float sd[NTOK];                  // 8 KB diffusion
  for (int i = threadIdx.x; i < NTOK; i += 256) {
    ((float2*)sr)[i] = ((const float2*)(pc + (size_t)b * NTOK * 2))[i];
    sd[i] = diffu[b * NTOK + i];
  }
  __syncthreads();

  const float T = thr[b];
  const int wave = threadIdx.x >> 6, lane = threadIdx.x & 63;
  __shared__ float red[4][2];

  for (int rs = 0; rs < 4; ++rs) {
    const int s = s0 + rs;
    const float r0 = sr[2 * s], r1 = sr[2 * s + 1];
    float v[8];
    float rowsum = 0.f, dot = 0.f;
    #pragma unroll
    for (int i = 0; i < 8; ++i) {
      const int t = threadIdx.x + i * 256;
      const float d0 = r0 * (1.0f - sr[2 * t]);
      const float d1 = r1 * (1.0f - sr[2 * t + 1]);
      const float q = d0 * d0 + d1 * d1;
      float val = 0.0f;
      if (q <= T) {
        // cos(atan2(d1,d0)) = d0/sqrt(q); q==0 -> atan2(0,0)=0 -> cos=1, bias=1
        val = (q > 0.0f) ? 0.5f * (1.0f + d0 * rsqrtf(q)) * __expf(-q) : 1.0f;
      }
      v[i] = val;
      rowsum += val;
      dot += val * sd[t];
    }
    rowsum = wave_reduce_add(rowsum);
    dot    = wave_reduce_add(dot);
    if (lane == 0) { red[wave][0] = rowsum; red[wave][1] = dot; }
    __syncthreads();
    const float rtot = red[0][0] + red[1][0] + red[2][0] + red[3][0];
    const float dtot = red[0][1] + red[1][1] + red[2][1] + red[3][1];
    const float sc = 1.0f / (rtot + 1e-8f);
    float* arow = attn + ((size_t)(b * NTOK + s)) * NTOK;
    #pragma unroll
    for (int i = 0; i < 8; ++i)
      arow[threadIdx.x + i * 256] = v[i] * sc;
    if (threadIdx.x == 0) dfield[b * NTOK + s] = dtot * sc;
    __syncthreads();
  }
}

extern "C" void kernel_launch(void* const* d_in, const int* in_sizes, int n_in,
                              void* d_out, int out_size, void* d_ws, size_t ws_size,
                              hipStream_t stream) {
  const float* pc = (const float*)d_in[0];
  const float* W1 = (const float*)d_in[1];
  const float* b1 = (const float*)d_in[2];
  const float* W2 = (const float*)d_in[3];
  const float* b2 = (const float*)d_in[4];
  const float* Wd = (const float*)d_in[5];
  const float* bd = (const float*)d_in[6];
  const float* Wr = (const float*)d_in[7];
  const float* br = (const float*)d_in[8];
  const float* Wm = (const float*)d_in[9];
  const float* bm = (const float*)d_in[10];

  float* out    = (float*)d_out;
  float* outd   = out;                          // diffusion  [B*N]
  float* outr   = out + BB * NTOK;              // reaction   [B*N]
  float* outm   = out + 2 * BB * NTOK;          // migration  [B*N]
  float* attn   = out + 3 * BB * NTOK;          // attn       [B*N*N]
  float* dfield = attn + (size_t)BB * NTOK * NTOK;  // diffusion_field [B*N]

  double* part = (double*)d_ws;                 // [BB][STATS_BLOCKS][2] partials
  float*  thr  = (float*)((char*)d_ws + (size_t)BB * STATS_BLOCKS * 2 * sizeof(double));

  hipLaunchKernelGGL(mlp_kernel, dim3(256), dim3(256), 0, stream,
                     pc, W1, b1, W2, b2, Wd, bd, Wr, br, Wm, bm, outd, outr, outm);
  hipLaunchKernelGGL(stats_kernel, dim3(STATS_BLOCKS, BB), dim3(256), 0, stream, pc, part);
  hipLaunchKernelGGL(finalize_kernel, dim3(1), dim3(64), 0, stream, part, thr);
  hipLaunchKernelGGL(attn_kernel, dim3(NTOK / 4, BB), dim3(256), 0, stream,
                     pc, outd, thr, attn, dfield);
}

// Round 2
// 38.654 us; speedup vs baseline: 2.0192x; 2.0192x over previous
//
#include <hip/hip_runtime.h>
#include <math.h>

#define NTOK 2048
#define HID  128
#define BB   4

__device__ __forceinline__ float wave_red_f(float v) {
  #pragma unroll
  for (int o = 32; o; o >>= 1) v += __shfl_down(v, o, 64);
  return v;
}
__device__ __forceinline__ double wave_red_d(double v) {
  #pragma unroll
  for (int o = 32; o; o >>= 1) v += __shfl_down(v, o, 64);
  return v;
}

// ---- Kernel A: blocks 0..255 = MLP (32 rows each, 8 rows/wave);
// ----           blocks 256..259 = per-batch threshold via separable moments.
__global__ __launch_bounds__(256) void mlp_thr_kernel(
    const float* __restrict__ pc,
    const float* __restrict__ W1, const float* __restrict__ b1,
    const float* __restrict__ W2, const float* __restrict__ b2,
    const float* __restrict__ Wd, const float* __restrict__ bd,
    const float* __restrict__ Wr, const float* __restrict__ br,
    const float* __restrict__ Wm, const float* __restrict__ bm,
    float* __restrict__ outd, float* __restrict__ outr, float* __restrict__ outm,
    float* __restrict__ thr)
{
  const int tid = threadIdx.x, wave = tid >> 6, lane = tid & 63;

  if (blockIdx.x >= 256) {
    // ---------------- threshold path (separable O(N) moments, f64) ---------
    const int b = blockIdx.x - 256;
    const float2* r = (const float2*)(pc + (size_t)b * NTOK * 2);
    double m[10];
    #pragma unroll
    for (int j = 0; j < 10; ++j) m[j] = 0.0;
    for (int i = tid; i < NTOK; i += 256) {
      const float2 c = r[i];
      const double a = c.x, bq = c.y, u = 1.0 - (double)c.x, v = 1.0 - (double)c.y;
      const double a2 = a * a, b2v = bq * bq, u2 = u * u, v2 = v * v;
      m[0] += a2;       m[1] += b2v;
      m[2] += a2 * a2;  m[3] += b2v * b2v;  m[4] += a2 * b2v;
      m[5] += u2;       m[6] += v2;
      m[7] += u2 * u2;  m[8] += v2 * v2;    m[9] += u2 * v2;
    }
    #pragma unroll
    for (int j = 0; j < 10; ++j) m[j] = wave_red_d(m[j]);
    __shared__ double sm[4][10];
    if (lane == 0) {
      #pragma unroll
      for (int j = 0; j < 10; ++j) sm[wave][j] = m[j];
    }
    __syncthreads();
    if (tid == 0) {
      double t[10];
      #pragma unroll
      for (int j = 0; j < 10; ++j)
        t[j] = sm[0][j] + sm[1][j] + sm[2][j] + sm[3][j];
      const double Sq  = t[0] * t[5] + t[1] * t[6];
      const double Sqq = t[2] * t[7] + 2.0 * t[4] * t[9] + t[3] * t[8];
      const double M = (double)NTOK * (double)NTOK;
      const double mean = Sq / M;
      double var = (Sqq - Sq * Sq / M) / (M - 1.0);
      if (var < 0.0) var = 0.0;
      double sd = sqrt(var);
      if (sd < 1e-6) sd = 1e-6;
      thr[b] = (float)(mean + 1.25 * sd);
    }
    return;
  }

  // ---------------- MLP path --------------------------------------------
  __shared__ float sW2[HID * HID];      // 64 KB
  __shared__ float sh1[4][8][HID];      // 16 KB
  for (int i = tid; i < HID * HID; i += 256) sW2[i] = W2[i];
  __syncthreads();

  const int j0 = lane, j1 = lane + 64;
  const float w10_0 = W1[j0], w11_0 = W1[HID + j0], b1_0 = b1[j0];
  const float w10_1 = W1[j1], w11_1 = W1[HID + j1], b1_1 = b1[j1];
  const float b2_0 = b2[j0], b2_1 = b2[j1];
  const float wd0 = Wd[j0], wd1 = Wd[j1];
  const float wr0 = Wr[j0], wr1 = Wr[j1];
  const float wm0 = Wm[j0], wm1 = Wm[j1];
  const float bdv = bd[0], brv = br[0], bmv = bm[0];

  const int row0 = blockIdx.x * 32 + wave * 8;    // 8 rows per wave

  // phase 1: h1 = silu(x@W1+b1) -> LDS (wave-private slab, no barrier needed)
  #pragma unroll
  for (int rr = 0; rr < 8; ++rr) {
    const float x0 = pc[(row0 + rr) * 2];
    const float x1 = pc[(row0 + rr) * 2 + 1];
    const float z0 = fmaf(x0, w10_0, fmaf(x1, w11_0, b1_0));
    const float z1 = fmaf(x0, w10_1, fmaf(x1, w11_1, b1_1));
    sh1[wave][rr][j0] = z0 / (1.f + __expf(-z0));
    sh1[wave][rr][j1] = z1 / (1.f + __expf(-z1));
  }

  // phase 2: h2 = h1 @ W2 + b2, 8 rows x 2 cols per lane, k in quads
  float a0[8], a1[8];
  #pragma unroll
  for (int rr = 0; rr < 8; ++rr) { a0[rr] = b2_0; a1[rr] = b2_1; }
  for (int kq = 0; kq < HID / 4; ++kq) {
    float4 h[8];
    #pragma unroll
    for (int rr = 0; rr < 8; ++rr)
      h[rr] = *(const float4*)&sh1[wave][rr][kq * 4];
    #pragma unroll
    for (int i = 0; i < 4; ++i) {
      const float wA = sW2[(kq * 4 + i) * HID + j0];
      const float wB = sW2[(kq * 4 + i) * HID + j1];
      #pragma unroll
      for (int rr = 0; rr < 8; ++rr) {
        const float hv = ((const float*)&h[rr])[i];
        a0[rr] = fmaf(hv, wA, a0[rr]);
        a1[rr] = fmaf(hv, wB, a1[rr]);
      }
    }
  }

  // phase 3: three 1-dim heads, wave reduce
  #pragma unroll
  for (int rr = 0; rr < 8; ++rr) {
    float dd = fmaf(a0[rr], wd0, a1[rr] * wd1);
    float rv = fmaf(a0[rr], wr0, a1[rr] * wr1);
    float mv = fmaf(a0[rr], wm0, a1[rr] * wm1);
    dd = wave_red_f(dd);
    rv = wave_red_f(rv);
    mv = wave_red_f(mv);
    if (lane == 0) {
      outd[row0 + rr] = dd + bdv;
      outr[row0 + rr] = rv + brv;
      outm[row0 + rr] = mv + bmv;
    }
  }
}

// ---- Kernel B: attn rows + diffusion_field, fused mask/normalize ----------
__global__ __launch_bounds__(256) void attn_kernel(
    const float* __restrict__ pc, const float* __restrict__ diffu,
    const float* __restrict__ thr,
    float* __restrict__ attn, float* __restrict__ dfield)
{
  const int b = blockIdx.y;
  const int tid = threadIdx.x, wave = tid >> 6, lane = tid & 63;
  __shared__ float2 su[NTOK];           // (1-r_t0, 1-r_t1), 16 KB
  __shared__ float  sd[NTOK];           // diffusion, 8 KB
  for (int i = tid; i < NTOK; i += 256) {
    const float2 c = ((const float2*)(pc + (size_t)b * NTOK * 2))[i];
    su[i] = make_float2(1.f - c.x, 1.f - c.y);
    sd[i] = diffu[b * NTOK + i];
  }
  __syncthreads();

  const float T = thr[b];
  __shared__ float red[2][4][2];
  const int s0 = blockIdx.x * 4;

  for (int rs = 0; rs < 4; ++rs) {
    const int s = s0 + rs;
    const float r0 = pc[((size_t)b * NTOK + s) * 2];
    const float r1 = pc[((size_t)b * NTOK + s) * 2 + 1];
    float v[8];
    float rsum = 0.f, dot = 0.f;
    #pragma unroll
    for (int i = 0; i < 8; ++i) {
      const int t = tid + i * 256;
      const float2 u = su[t];
      const float d0 = r0 * u.x;
      const float d1 = r1 * u.y;
      const float q = fmaf(d0, d0, d1 * d1);
      float val = 0.f;
      if (q <= T)
        val = (q > 0.f) ? 0.5f * (1.f + d0 * rsqrtf(q)) * __expf(-q) : 1.f;
      v[i] = val;
      rsum += val;
      dot = fmaf(val, sd[t], dot);
    }
    rsum = wave_red_f(rsum);
    dot  = wave_red_f(dot);
    if (lane == 0) { red[rs & 1][wave][0] = rsum; red[rs & 1][wave][1] = dot; }
    __syncthreads();
    const float rtot = red[rs & 1][0][0] + red[rs & 1][1][0] +
                       red[rs & 1][2][0] + red[rs & 1][3][0];
    const float dtot = red[rs & 1][0][1] + red[rs & 1][1][1] +
                       red[rs & 1][2][1] + red[rs & 1][3][1];
    const float sc = 1.f / (rtot + 1e-8f);
    float* arow = attn + ((size_t)b * NTOK + s) * NTOK;
    #pragma unroll
    for (int i = 0; i < 8; ++i)
      __builtin_nontemporal_store(v[i] * sc, arow + tid + i * 256);
    if (tid == 0) dfield[b * NTOK + s] = dtot * sc;
  }
}

extern "C" void kernel_launch(void* const* d_in, const int* in_sizes, int n_in,
                              void* d_out, int out_size, void* d_ws, size_t ws_size,
                              hipStream_t stream) {
  const float* pc = (const float*)d_in[0];
  const float* W1 = (const float*)d_in[1];
  const float* b1 = (const float*)d_in[2];
  const float* W2 = (const float*)d_in[3];
  const float* b2 = (const float*)d_in[4];
  const float* Wd = (const float*)d_in[5];
  const float* bd = (const float*)d_in[6];
  const float* Wr = (const float*)d_in[7];
  const float* br = (const float*)d_in[8];
  const float* Wm = (const float*)d_in[9];
  const float* bm = (const float*)d_in[10];

  float* out    = (float*)d_out;
  float* outd   = out;                                // diffusion  [B*N]
  float* outr   = out + BB * NTOK;                    // reaction   [B*N]
  float* outm   = out + 2 * BB * NTOK;                // migration  [B*N]
  float* attn   = out + 3 * BB * NTOK;                // attn       [B*N*N]
  float* dfield = attn + (size_t)BB * NTOK * NTOK;    // diffusion_field [B*N]

  float* thr = (float*)d_ws;                          // [BB]

  hipLaunchKernelGGL(mlp_thr_kernel, dim3(256 + BB), dim3(256), 0, stream,
                     pc, W1, b1, W2, b2, Wd, bd, Wr, br, Wm, bm,
                     outd, outr, outm, thr);
  hipLaunchKernelGGL(attn_kernel, dim3(NTOK / 4, BB), dim3(256), 0, stream,
                     pc, outd, thr, attn, dfield);
}

// Round 4
// 35.813 us; speedup vs baseline: 2.1793x; 1.0793x over previous
//
#include <hip/hip_runtime.h>
#include <math.h>

#define NTOK 2048
#define HID  128
#define BB   4

typedef float f32x4 __attribute__((ext_vector_type(4)));

__device__ __forceinline__ float wave_red_f(float v) {
  #pragma unroll
  for (int o = 32; o; o >>= 1) v += __shfl_down(v, o, 64);
  return v;
}
__device__ __forceinline__ double wave_red_d(double v) {
  #pragma unroll
  for (int o = 32; o; o >>= 1) v += __shfl_down(v, o, 64);
  return v;
}

// ---- Kernel A: blocks 0..255 = MLP (32 rows each, 8 rows/wave);
// ----           blocks 256..259 = per-batch threshold via separable moments.
__global__ __launch_bounds__(256) void mlp_thr_kernel(
    const float* __restrict__ pc,
    const float* __restrict__ W1, const float* __restrict__ b1,
    const float* __restrict__ W2, const float* __restrict__ b2,
    const float* __restrict__ Wd, const float* __restrict__ bd,
    const float* __restrict__ Wr, const float* __restrict__ br,
    const float* __restrict__ Wm, const float* __restrict__ bm,
    float* __restrict__ outd, float* __restrict__ outr, float* __restrict__ outm,
    float* __restrict__ thr)
{
  const int tid = threadIdx.x, wave = tid >> 6, lane = tid & 63;

  if (blockIdx.x >= 256) {
    // ---------------- threshold path (separable O(N) moments, f64) ---------
    const int b = blockIdx.x - 256;
    const float2* r = (const float2*)(pc + (size_t)b * NTOK * 2);
    double m[10];
    #pragma unroll
    for (int j = 0; j < 10; ++j) m[j] = 0.0;
    for (int i = tid; i < NTOK; i += 256) {
      const float2 c = r[i];
      const double a = c.x, bq = c.y, u = 1.0 - (double)c.x, v = 1.0 - (double)c.y;
      const double a2 = a * a, b2v = bq * bq, u2 = u * u, v2 = v * v;
      m[0] += a2;       m[1] += b2v;
      m[2] += a2 * a2;  m[3] += b2v * b2v;  m[4] += a2 * b2v;
      m[5] += u2;       m[6] += v2;
      m[7] += u2 * u2;  m[8] += v2 * v2;    m[9] += u2 * v2;
    }
    #pragma unroll
    for (int j = 0; j < 10; ++j) m[j] = wave_red_d(m[j]);
    __shared__ double sm[4][10];
    if (lane == 0) {
      #pragma unroll
      for (int j = 0; j < 10; ++j) sm[wave][j] = m[j];
    }
    __syncthreads();
    if (tid == 0) {
      double t[10];
      #pragma unroll
      for (int j = 0; j < 10; ++j)
        t[j] = sm[0][j] + sm[1][j] + sm[2][j] + sm[3][j];
      const double Sq  = t[0] * t[5] + t[1] * t[6];
      const double Sqq = t[2] * t[7] + 2.0 * t[4] * t[9] + t[3] * t[8];
      const double M = (double)NTOK * (double)NTOK;
      const double mean = Sq / M;
      double var = (Sqq - Sq * Sq / M) / (M - 1.0);
      if (var < 0.0) var = 0.0;
      double sd = sqrt(var);
      if (sd < 1e-6) sd = 1e-6;
      thr[b] = (float)(mean + 1.25 * sd);
    }
    return;
  }

  // ---------------- MLP path --------------------------------------------
  __shared__ float sW2[HID * HID];      // 64 KB
  __shared__ float sh1[4][8][HID];      // 16 KB
  for (int i = tid; i < HID * HID; i += 256) sW2[i] = W2[i];
  __syncthreads();

  const int j0 = lane, j1 = lane + 64;
  const float w10_0 = W1[j0], w11_0 = W1[HID + j0], b1_0 = b1[j0];
  const float w10_1 = W1[j1], w11_1 = W1[HID + j1], b1_1 = b1[j1];
  const float b2_0 = b2[j0], b2_1 = b2[j1];
  const float wd0 = Wd[j0], wd1 = Wd[j1];
  const float wr0 = Wr[j0], wr1 = Wr[j1];
  const float wm0 = Wm[j0], wm1 = Wm[j1];
  const float bdv = bd[0], brv = br[0], bmv = bm[0];

  const int row0 = blockIdx.x * 32 + wave * 8;    // 8 rows per wave

  // phase 1: h1 = silu(x@W1+b1) -> LDS (wave-private slab, no barrier needed)
  #pragma unroll
  for (int rr = 0; rr < 8; ++rr) {
    const float x0 = pc[(row0 + rr) * 2];
    const float x1 = pc[(row0 + rr) * 2 + 1];
    const float z0 = fmaf(x0, w10_0, fmaf(x1, w11_0, b1_0));
    const float z1 = fmaf(x0, w10_1, fmaf(x1, w11_1, b1_1));
    sh1[wave][rr][j0] = z0 / (1.f + __expf(-z0));
    sh1[wave][rr][j1] = z1 / (1.f + __expf(-z1));
  }

  // phase 2: h2 = h1 @ W2 + b2, 8 rows x 2 cols per lane, k in quads
  float a0[8], a1[8];
  #pragma unroll
  for (int rr = 0; rr < 8; ++rr) { a0[rr] = b2_0; a1[rr] = b2_1; }
  for (int kq = 0; kq < HID / 4; ++kq) {
    float4 h[8];
    #pragma unroll
    for (int rr = 0; rr < 8; ++rr)
      h[rr] = *(const float4*)&sh1[wave][rr][kq * 4];
    #pragma unroll
    for (int i = 0; i < 4; ++i) {
      const float wA = sW2[(kq * 4 + i) * HID + j0];
      const float wB = sW2[(kq * 4 + i) * HID + j1];
      #pragma unroll
      for (int rr = 0; rr < 8; ++rr) {
        const float hv = ((const float*)&h[rr])[i];
        a0[rr] = fmaf(hv, wA, a0[rr]);
        a1[rr] = fmaf(hv, wB, a1[rr]);
      }
    }
  }

  // phase 3: three 1-dim heads, wave reduce
  #pragma unroll
  for (int rr = 0; rr < 8; ++rr) {
    float dd = fmaf(a0[rr], wd0, a1[rr] * wd1);
    float rv = fmaf(a0[rr], wr0, a1[rr] * wr1);
    float mv = fmaf(a0[rr], wm0, a1[rr] * wm1);
    dd = wave_red_f(dd);
    rv = wave_red_f(rv);
    mv = wave_red_f(mv);
    if (lane == 0) {
      outd[row0 + rr] = dd + bdv;
      outr[row0 + rr] = rv + brv;
      outm[row0 + rr] = mv + bmv;
    }
  }
}

// ---- Kernel B: attn rows + diffusion_field, register-resident columns -----
// Thread tid owns columns t = tid*4+j (j=0..3) and t = 1024 + tid*4+j,
// fixed across all 4 rows of the block -> (1-r_t) and diffusion[t] live in
// registers; no LDS staging at all. Stores are float4 nontemporal.
__global__ __launch_bounds__(256, 6) void attn_kernel(
    const float* __restrict__ pc, const float* __restrict__ diffu,
    const float* __restrict__ thr,
    float* __restrict__ attn, float* __restrict__ dfield)
{
  const int b = blockIdx.y;
  const int tid = threadIdx.x, wave = tid >> 6, lane = tid & 63;

  const float2* __restrict__ rr  = (const float2*)(pc + (size_t)b * NTOK * 2);
  const float4* __restrict__ rr4 = (const float4*)rr;
  const float4* __restrict__ sd4 = (const float4*)(diffu + b * NTOK);

  float2 u[8];
  float  sdr[8];
  #pragma unroll
  for (int i = 0; i < 2; ++i) {
    const float4 c0 = rr4[tid * 2 + i * 512];
    const float4 c1 = rr4[tid * 2 + 1 + i * 512];
    u[i * 4 + 0] = make_float2(1.f - c0.x, 1.f - c0.y);
    u[i * 4 + 1] = make_float2(1.f - c0.z, 1.f - c0.w);
    u[i * 4 + 2] = make_float2(1.f - c1.x, 1.f - c1.y);
    u[i * 4 + 3] = make_float2(1.f - c1.z, 1.f - c1.w);
    const float4 dv = sd4[tid + i * 256];
    sdr[i * 4 + 0] = dv.x; sdr[i * 4 + 1] = dv.y;
    sdr[i * 4 + 2] = dv.z; sdr[i * 4 + 3] = dv.w;
  }

  const float T = thr[b];
  __shared__ float red[2][4][2];
  const int s0 = blockIdx.x * 4;

  for (int rs = 0; rs < 4; ++rs) {
    const int s = s0 + rs;
    const float2 rc = rr[s];                  // block-uniform -> scalar load
    float v[8];
    float rsum = 0.f, dot = 0.f;
    #pragma unroll
    for (int k = 0; k < 8; ++k) {
      const float d0 = rc.x * u[k].x;
      const float d1 = rc.y * u[k].y;
      const float q = fmaf(d0, d0, d1 * d1);
      float val = 0.f;
      if (q <= T)
        val = (q > 0.f) ? 0.5f * (1.f + d0 * rsqrtf(q)) * __expf(-q) : 1.f;
      v[k] = val;
      rsum += val;
      dot = fmaf(val, sdr[k], dot);
    }
    rsum = wave_red_f(rsum);
    dot  = wave_red_f(dot);
    if (lane == 0) { red[rs & 1][wave][0] = rsum; red[rs & 1][wave][1] = dot; }
    __syncthreads();
    const float rtot = red[rs & 1][0][0] + red[rs & 1][1][0] +
                       red[rs & 1][2][0] + red[rs & 1][3][0];
    const float dtot = red[rs & 1][0][1] + red[rs & 1][1][1] +
                       red[rs & 1][2][1] + red[rs & 1][3][1];
    const float sc = 1.f / (rtot + 1e-8f);
    f32x4* arow4 = (f32x4*)(attn + ((size_t)b * NTOK + s) * NTOK);
    #pragma unroll
    for (int i = 0; i < 2; ++i) {
      f32x4 o;
      o.x = v[i * 4 + 0] * sc; o.y = v[i * 4 + 1] * sc;
      o.z = v[i * 4 + 2] * sc; o.w = v[i * 4 + 3] * sc;
      __builtin_nontemporal_store(o, arow4 + tid + i * 256);
    }
    if (tid == 0) dfield[b * NTOK + s] = dtot * sc;
  }
}

extern "C" void kernel_launch(void* const* d_in, const int* in_sizes, int n_in,
                              void* d_out, int out_size, void* d_ws, size_t ws_size,
                              hipStream_t stream) {
  const float* pc = (const float*)d_in[0];
  const float* W1 = (const float*)d_in[1];
  const float* b1 = (const float*)d_in[2];
  const float* W2 = (const float*)d_in[3];
  const float* b2 = (const float*)d_in[4];
  const float* Wd = (const float*)d_in[5];
  const float* bd = (const float*)d_in[6];
  const float* Wr = (const float*)d_in[7];
  const float* br = (const float*)d_in[8];
  const float* Wm = (const float*)d_in[9];
  const float* bm = (const float*)d_in[10];

  float* out    = (float*)d_out;
  float* outd   = out;                                // diffusion  [B*N]
  float* outr   = out + BB * NTOK;                    // reaction   [B*N]
  float* outm   = out + 2 * BB * NTOK;                // migration  [B*N]
  float* attn   = out + 3 * BB * NTOK;                // attn       [B*N*N]
  float* dfield = attn + (size_t)BB * NTOK * NTOK;    // diffusion_field [B*N]

  float* thr = (float*)d_ws;                          // [BB]

  hipLaunchKernelGGL(mlp_thr_kernel, dim3(256 + BB), dim3(256), 0, stream,
                     pc, W1, b1, W2, b2, Wd, bd, Wr, br, Wm, bm,
                     outd, outr, outm, thr);
  hipLaunchKernelGGL(attn_kernel, dim3(NTOK / 4, BB), dim3(256), 0, stream,
                     pc, outd, thr, attn, dfield);
}